// Round 10
// baseline (395.420 us; speedup 1.0000x reference)
//
#include <hip/hip_runtime.h>
#include <hip/hip_fp16.h>

#define F16 _Float16
typedef F16 f16x8 __attribute__((ext_vector_type(8)));
typedef F16 f16x4 __attribute__((ext_vector_type(4)));
typedef float f32x4 __attribute__((ext_vector_type(4)));

// ---------------- f32 -> f16 convert (vectorized) ----------------
__global__ void cvt_f32_f16(const float* __restrict__ src, F16* __restrict__ dst, int n) {
    int idx = blockIdx.x * blockDim.x + threadIdx.x;
    int stride = gridDim.x * blockDim.x;
    for (int i = idx * 4; i < n; i += stride * 4) {
        float4 v = *reinterpret_cast<const float4*>(src + i);
        f16x4 o;
        o[0] = (F16)v.x; o[1] = (F16)v.y; o[2] = (F16)v.z; o[3] = (F16)v.w;
        *reinterpret_cast<f16x4*>(dst + i) = o;
    }
}

// ---------------- async global->LDS 16B ----------------
__device__ __forceinline__ void gl_lds16(const F16* g, F16* l) {
    __builtin_amdgcn_global_load_lds(
        (const __attribute__((address_space(1))) void*)g,
        (__attribute__((address_space(3))) void*)l, 16, 0, 0);
}

// ---------------- unified 128x256 GEMM (T3+T4+T5), 8 waves 2Mx4N ----------------
// C[M][N] = A[M][K] * Bw[N][K]^T. BK=64, wave tile 64x64 = 4x4 frags,
// 2 phases/K-tile x 16 MFMA. LDS [2buf][A(128x64)|B0|B1] = 96KB fragment-order.
// Staging: A of S(t+1) at p0 (2), B of S(t+2) at p1 (4); vmcnt(4)/tile, never 0 mid-loop.
// XCD 2-D chunk: 8 XCDs as XM x XN, each owns CM x CN contiguous blocks.
// EPI==0: QKV scatter epilogue (q pre-scaled, v transposed [B,H,D,S]); EPI==1: f32+bias.
template <int EPI, int XM, int CM, int CN>
__global__ __launch_bounds__(512, 2) void gemm128(
    const F16* __restrict__ A, const F16* __restrict__ Bw, const float* __restrict__ bias,
    F16* __restrict__ q_ws, F16* __restrict__ k_ws, F16* __restrict__ v_ws,
    float* __restrict__ fout, int M, int N, int K)
{
    __shared__ __align__(16) F16 lds[2][3][8192];  // 96 KiB
    const int tid = threadIdx.x;
    const int w = tid >> 6, l = tid & 63;
    const int lr = l & 15, lg = l >> 4;
    const int wm = w >> 2, wn = w & 3;

    const int xcd = (int)blockIdx.x & 7, s5 = (int)blockIdx.x >> 3;
    const int mb = (xcd % XM) * CM + s5 / CN;
    const int nb = (xcd / XM) * CN + s5 % CN;
    const long brow = (long)mb * 128, bcol = (long)nb * 256;

    const F16* rbA = A + brow * K;
    const F16* rb2 = Bw + bcol * K;
    const F16* rb3 = rb2 + 128 * (long)K;

    const int sr0 = ((tid >> 7) << 4) + (tid & 15);
    const int skk = (((tid >> 6) & 1) << 5) + (((tid >> 4) & 3) << 3);
    const int wb8 = (w << 6) * 8;

#define GISSUE(BUF, R, S, KT, RB) \
    gl_lds16(RB + (long)(sr0 + S * 64) * K + (KT) * 64 + skk, \
             &lds[BUF][R][S * 4096 + wb8])

    const int NK = K >> 6;

    f32x4 acc[4][4];
#pragma unroll
    for (int f = 0; f < 4; ++f)
#pragma unroll
        for (int nf = 0; nf < 4; ++nf) acc[f][nf] = f32x4{0.f, 0.f, 0.f, 0.f};

    // prologue: S(0) full (6), S(1) B (4); wait vmcnt(4)
    GISSUE(0, 0, 0, 0, rbA); GISSUE(0, 0, 1, 0, rbA);
    GISSUE(0, 1, 0, 0, rb2); GISSUE(0, 1, 1, 0, rb2);
    GISSUE(0, 2, 0, 0, rb3); GISSUE(0, 2, 1, 0, rb3);
    if (NK > 1) {
        GISSUE(1, 1, 0, 1, rb2); GISSUE(1, 1, 1, 1, rb2);
        GISSUE(1, 2, 0, 1, rb3); GISSUE(1, 2, 1, 1, rb3);
        asm volatile("s_waitcnt vmcnt(4)" ::: "memory");
    } else {
        asm volatile("s_waitcnt vmcnt(0)" ::: "memory");
    }
    __builtin_amdgcn_s_barrier();

    for (int kt = 0; kt < NK; ++kt) {
        const int cur = kt & 1, nxt = cur ^ 1;
        const F16* Areg = &lds[cur][0][0];
        const F16* Breg = &lds[cur][1 + (wn >> 1)][0];
        f16x8 b[4][2];
#pragma unroll
        for (int nf = 0; nf < 4; ++nf)
#pragma unroll
            for (int ks = 0; ks < 2; ++ks)
                b[nf][ks] = *reinterpret_cast<const f16x8*>(
                    Breg + ((((wn & 1) * 4 + nf) * 2 + ks) * 64 + l) * 8);
#pragma unroll
        for (int p = 0; p < 2; ++p) {
            f16x8 a[2][2];
#pragma unroll
            for (int mf = 0; mf < 2; ++mf)
#pragma unroll
                for (int ks = 0; ks < 2; ++ks)
                    a[mf][ks] = *reinterpret_cast<const f16x8*>(
                        Areg + (((wm * 4 + 2 * p + mf) * 2 + ks) * 64 + l) * 8);
            if (p == 0) {
                if (kt + 1 < NK) { GISSUE(nxt, 0, 0, kt + 1, rbA); GISSUE(nxt, 0, 1, kt + 1, rbA); }
            } else {
                if (kt + 2 < NK) {
                    GISSUE(cur, 1, 0, kt + 2, rb2); GISSUE(cur, 1, 1, kt + 2, rb2);
                    GISSUE(cur, 2, 0, kt + 2, rb3); GISSUE(cur, 2, 1, kt + 2, rb3);
                }
            }
            __builtin_amdgcn_sched_barrier(0);
            __builtin_amdgcn_s_barrier();
            asm volatile("s_waitcnt lgkmcnt(0)" ::: "memory");
            __builtin_amdgcn_sched_barrier(0);
            __builtin_amdgcn_s_setprio(1);
#pragma unroll
            for (int mf = 0; mf < 2; ++mf)
#pragma unroll
                for (int nf = 0; nf < 4; ++nf)
#pragma unroll
                    for (int ks = 0; ks < 2; ++ks)
                        acc[2 * p + mf][nf] = __builtin_amdgcn_mfma_f32_16x16x32_f16(
                            a[mf][ks], b[nf][ks], acc[2 * p + mf][nf], 0, 0, 0);
            __builtin_amdgcn_s_setprio(0);
            __builtin_amdgcn_sched_barrier(0);
            if (p == 1) {
                if (kt + 2 < NK) asm volatile("s_waitcnt vmcnt(4)" ::: "memory");
                else             asm volatile("s_waitcnt vmcnt(0)" ::: "memory");
            }
            __builtin_amdgcn_s_barrier();
        }
    }
#undef GISSUE

    // ---- epilogue (C/D layout: row=lg*4+reg, col=lr) ----
    const int col0 = (int)bcol + wn * 64;
    const int row0 = (int)brow + wm * 64;
    if constexpr (EPI == 0) {
        const int part = (int)(bcol >> 11);        // 0=q 1=k 2=v (256-col block never crosses)
        const int bI = row0 >> 10;                 // batch (64-row span never crosses)
        const int sb = row0 & 1023;
        const float scl = (part == 0) ? 0.08838834764831845f : 1.0f;  // 1/sqrt(128)
#pragma unroll
        for (int nf = 0; nf < 4; ++nf) {
            const int gcol = col0 + nf * 16 + lr;
            const float bv = bias[gcol];
            const int d = gcol & 127;
            const int hh = (gcol >> 7) & 15;
            if (part == 2) {
                F16* dst0 = v_ws + ((long)((bI * 16 + hh) * 128 + d)) * 1024;
#pragma unroll
                for (int f = 0; f < 4; ++f) {
                    f16x4 pv;
#pragma unroll
                    for (int r = 0; r < 4; ++r) pv[r] = (F16)(acc[f][nf][r] + bv);
                    *reinterpret_cast<f16x4*>(dst0 + sb + f * 16 + lg * 4) = pv;
                }
            } else {
                F16* dst0 = ((part == 0) ? q_ws : k_ws) + ((long)(bI * 16 + hh) * 1024) * 128 + d;
#pragma unroll
                for (int f = 0; f < 4; ++f)
#pragma unroll
                    for (int r = 0; r < 4; ++r)
                        dst0[(long)(sb + f * 16 + lg * 4 + r) * 128] =
                            (F16)((acc[f][nf][r] + bv) * scl);
            }
        }
    } else {
#pragma unroll
        for (int nf = 0; nf < 4; ++nf) {
            const int gcol = col0 + nf * 16 + lr;
            const float bv = bias[gcol];
#pragma unroll
            for (int f = 0; f < 4; ++f)
#pragma unroll
                for (int r = 0; r < 4; ++r)
                    fout[(long)(row0 + f * 16 + lg * 4 + r) * N + gcol] = acc[f][nf][r] + bv;
        }
    }
}

// ---------------- flash attention v3 (unchanged from round 9) ----------------
__global__ __launch_bounds__(256, 2) void attn_kernel(
    const F16* __restrict__ q_ws, const F16* __restrict__ k_ws,
    const F16* __restrict__ v_ws, F16* __restrict__ ctx)
{
    __shared__ __align__(16) F16 kt[2][64 * 128];    // 32KB
    __shared__ __align__(16) F16 vt[2][128 * 64];    // 32KB
    __shared__ __align__(16) F16 plds[4][2][1024];   // 16KB
    const int tid = threadIdx.x;
    const int w = tid >> 6, l = tid & 63;
    const int lr = l & 15, lg = l >> 4;
    const int work = (blockIdx.x & 7) * 64 + (blockIdx.x >> 3);
    const int bh = work >> 3, qt = work & 7;
    const int b = bh >> 4, h = bh & 15;
    const int q0 = qt * 128 + w * 32;
    const int sw = (lr & 7) << 4;

    const F16* kbh = k_ws + (long)bh * 1024 * 128;
    const F16* vbh = v_ws + (long)bh * 128 * 1024;

    f16x8 qf[2][4];
#pragma unroll
    for (int mi = 0; mi < 2; ++mi)
#pragma unroll
        for (int ks = 0; ks < 4; ++ks)
            qf[mi][ks] = *reinterpret_cast<const f16x8*>(
                q_ws + ((long)bh * 1024 + q0 + mi * 16 + lr) * 128 + ks * 32 + lg * 8);

    auto stage = [&](int buf, int kv0) {
#pragma unroll
        for (int t = 0; t < 4; ++t) {
            const int chunk = t * 256 + tid;
            const int row = chunk >> 4;
            const int colb = (chunk & 15) << 4;
            const int gcol = colb ^ ((row & 7) << 4);
            gl_lds16(kbh + (long)(kv0 + row) * 128 + (gcol >> 1),
                     &kt[buf][(t * 256 + w * 64) * 8]);
        }
#pragma unroll
        for (int t = 0; t < 4; ++t) {
            const int chunk = t * 256 + tid;
            const int d = chunk >> 3;
            const int colb = (chunk & 7) << 4;
            const int gcol = colb ^ ((d & 7) << 4);
            gl_lds16(vbh + (long)d * 1024 + kv0 + (gcol >> 1),
                     &vt[buf][(t * 256 + w * 64) * 8]);
        }
    };

    float mrun[2], lsum[2];
    mrun[0] = mrun[1] = -1e30f;
    lsum[0] = lsum[1] = 0.f;
    f32x4 acc[2][8];
#pragma unroll
    for (int mi = 0; mi < 2; ++mi)
#pragma unroll
        for (int nf = 0; nf < 8; ++nf) acc[mi][nf] = f32x4{0.f, 0.f, 0.f, 0.f};

    stage(0, 0);
    __syncthreads();
    int cur = 0;
    for (int it = 0; it < 16; ++it) {
        if (it + 1 < 16) stage(cur ^ 1, (it + 1) * 64);

        f32x4 sc[2][4];
#pragma unroll
        for (int mi = 0; mi < 2; ++mi)
#pragma unroll
            for (int cf = 0; cf < 4; ++cf) sc[mi][cf] = f32x4{0.f, 0.f, 0.f, 0.f};
#pragma unroll
        for (int cf = 0; cf < 4; ++cf) {
#pragma unroll
            for (int ks = 0; ks < 4; ++ks) {
                const int row = cf * 16 + lr;
                const int eff = (ks * 64 + lg * 16) ^ ((row & 7) << 4);
                f16x8 kf = *reinterpret_cast<const f16x8*>(&kt[cur][row * 128 + (eff >> 1)]);
#pragma unroll
                for (int mi = 0; mi < 2; ++mi)
                    sc[mi][cf] = __builtin_amdgcn_mfma_f32_16x16x32_f16(kf, qf[mi][ks], sc[mi][cf], 0, 0, 0);
            }
        }

#pragma unroll
        for (int mi = 0; mi < 2; ++mi) {
            float nm = sc[mi][0][0];
#pragma unroll
            for (int cf = 0; cf < 4; ++cf)
#pragma unroll
                for (int r = 0; r < 4; ++r) nm = fmaxf(nm, sc[mi][cf][r]);
            nm = fmaxf(nm, __shfl_xor(nm, 16));
            nm = fmaxf(nm, __shfl_xor(nm, 32));
            const bool skip = __all(nm <= mrun[mi] + 8.0f);
            float mn, al;
            if (skip) { mn = mrun[mi]; al = 1.0f; }
            else      { mn = fmaxf(mrun[mi], nm); al = __expf(mrun[mi] - mn); mrun[mi] = mn; }
            float rs = 0.f;
            char* prow = reinterpret_cast<char*>(&plds[w][mi][0]) + lr * 128;
#pragma unroll
            for (int cf = 0; cf < 4; ++cf) {
                f16x4 pv;
#pragma unroll
                for (int r = 0; r < 4; ++r) {
                    const float pe = __expf(sc[mi][cf][r] - mn);
                    rs += pe;
                    pv[r] = (F16)pe;
                }
                *reinterpret_cast<f16x4*>(prow + ((cf * 32 + lg * 8) ^ sw)) = pv;
            }
            rs += __shfl_xor(rs, 16);
            rs += __shfl_xor(rs, 32);
            lsum[mi] = lsum[mi] * al + rs;
            if (!skip) {
#pragma unroll
                for (int nf = 0; nf < 8; ++nf)
#pragma unroll
                    for (int r = 0; r < 4; ++r) acc[mi][nf][r] *= al;
            }
        }

        f16x8 pf[2][2];
#pragma unroll
        for (int mi = 0; mi < 2; ++mi)
#pragma unroll
            for (int kvs = 0; kvs < 2; ++kvs)
                pf[mi][kvs] = *reinterpret_cast<const f16x8*>(
                    reinterpret_cast<char*>(&plds[w][mi][0]) + lr * 128 + ((kvs * 64 + lg * 16) ^ sw));
#pragma unroll
        for (int nf = 0; nf < 8; ++nf) {
#pragma unroll
            for (int kvs = 0; kvs < 2; ++kvs) {
                const int d = nf * 16 + lr;
                const int eff = (kvs * 64 + lg * 16) ^ ((d & 7) << 4);
                f16x8 vf = *reinterpret_cast<const f16x8*>(&vt[cur][d * 64 + (eff >> 1)]);
#pragma unroll
                for (int mi = 0; mi < 2; ++mi)
                    acc[mi][nf] = __builtin_amdgcn_mfma_f32_16x16x32_f16(vf, pf[mi][kvs], acc[mi][nf], 0, 0, 0);
            }
        }
        __syncthreads();
        cur ^= 1;
    }

#pragma unroll
    for (int mi = 0; mi < 2; ++mi) {
        const float inv = 1.f / lsum[mi];
        const int s = q0 + mi * 16 + lr;
        F16* orow = ctx + ((long)(b * 1024 + s)) * 2048 + h * 128;
#pragma unroll
        for (int nf = 0; nf < 8; ++nf) {
            f16x4 ov;
#pragma unroll
            for (int r = 0; r < 4; ++r) ov[r] = (F16)(acc[mi][nf][r] * inv);
            *reinterpret_cast<f16x4*>(orow + nf * 16 + lg * 4) = ov;
        }
    }
}

// ---------------- launch ----------------
extern "C" void kernel_launch(void* const* d_in, const int* in_sizes, int n_in,
                              void* d_out, int out_size, void* d_ws, size_t ws_size,
                              hipStream_t stream) {
    const float* query = (const float*)d_in[0];
    const float* w_in  = (const float*)d_in[1];
    const float* b_in  = (const float*)d_in[2];
    const float* w_out = (const float*)d_in[3];
    const float* b_out = (const float*)d_in[4];
    float* out = (float*)d_out;

    char* ws = (char*)d_ws;
    size_t off = 0;
    auto carve = [&](size_t bytes) -> void* {
        void* p = ws + off;
        off += (bytes + 255) & ~(size_t)255;
        return p;
    };
    F16* xq  = (F16*)carve(8388608ULL * 2);   // query f16 [4096][2048]
    F16* wih = (F16*)carve(12582912ULL * 2);  // in_proj_weight f16 [6144][2048]
    F16* woh = (F16*)carve(4194304ULL * 2);   // out_proj_weight f16 [2048][2048]
    F16* qws = (F16*)carve(8388608ULL * 2);   // Q [B,H,S,D] pre-scaled
    F16* kws = (F16*)carve(8388608ULL * 2);   // K [B,H,S,D]
    F16* vws = (F16*)carve(8388608ULL * 2);   // V [B,H,D,S] (transposed)
    F16* ctx = (F16*)carve(8388608ULL * 2);   // ctx [B,S,E]

    cvt_f32_f16<<<1024, 256, 0, stream>>>(query, xq, 8388608);
    cvt_f32_f16<<<1024, 256, 0, stream>>>(w_in, wih, 12582912);
    cvt_f32_f16<<<512, 256, 0, stream>>>(w_out, woh, 4194304);

    // QKV: M=4096 (32 mb), N=6144 (24 nb) -> grid 768 = 3 exact rounds.
    // XCD chunk 16mb x 6nb (XM=2, CM=16, CN=6).
    gemm128<0, 2, 16, 6><<<768, 512, 0, stream>>>(
        xq, wih, b_in, qws, kws, vws, nullptr, 4096, 6144, 2048);
    attn_kernel<<<512, 256, 0, stream>>>(qws, kws, vws, ctx);
    // out proj: M=4096 (32 mb), N=2048 (8 nb) -> grid 256 = 1/CU.
    // XCD chunk 8mb x 4nb (XM=4, CM=8, CN=4).
    gemm128<1, 4, 8, 4><<<256, 512, 0, stream>>>(
        ctx, woh, b_out, nullptr, nullptr, nullptr, out, 4096, 2048, 2048);
}